// Round 6
// baseline (1047.852 us; speedup 1.0000x reference)
//
#include <hip/hip_runtime.h>
#include <hip/hip_bf16.h>

typedef short s16x8 __attribute__((ext_vector_type(8)));
typedef float f32x4 __attribute__((ext_vector_type(4)));
typedef unsigned short u16x8 __attribute__((ext_vector_type(8)));

__device__ __forceinline__ float bf2f(unsigned short u){
  union { unsigned int i; float f; } v; v.i = ((unsigned int)u) << 16; return v.f;
}
__device__ __forceinline__ unsigned short f2bf(float f){
  union { float f; unsigned int i; } v; v.f = f;
  unsigned int x = v.i;
  return (unsigned short)((x + 0x7fffu + ((x >> 16) & 1u)) >> 16);
}
__device__ __forceinline__ short f2bs(float f){
  union { __hip_bfloat16 h; short s; } u; u.h = __float2bfloat16(f); return u.s;
}
__device__ __forceinline__ s16x8 cvt8(f32x4 a, f32x4 b){
  s16x8 r;
  r[0]=f2bs(a[0]); r[1]=f2bs(a[1]); r[2]=f2bs(a[2]); r[3]=f2bs(a[3]);
  r[4]=f2bs(b[0]); r[5]=f2bs(b[1]); r[6]=f2bs(b[2]); r[7]=f2bs(b[3]);
  return r;
}

// cast the 4 weight matrices (512x512 f32) to bf16 in one launch
__global__ __launch_bounds__(256) void cast_w(
    const float* __restrict__ w0, const float* __restrict__ w1,
    const float* __restrict__ w2, const float* __restrict__ w3,
    unsigned short* __restrict__ o0, unsigned short* __restrict__ o1,
    unsigned short* __restrict__ o2, unsigned short* __restrict__ o3)
{
  int g = blockIdx.x * 256 + threadIdx.x;
  int which = g >> 15;
  int off = (g & 32767) * 8;
  const float* src = which==0 ? w0 : which==1 ? w1 : which==2 ? w2 : w3;
  unsigned short* dst = which==0 ? o0 : which==1 ? o1 : which==2 ? o2 : o3;
  float4 a = *(const float4*)(src + off);
  float4 b = *(const float4*)(src + off + 4);
  u16x8 r;
  r[0]=f2bf(a.x); r[1]=f2bf(a.y); r[2]=f2bf(a.z); r[3]=f2bf(a.w);
  r[4]=f2bf(b.x); r[5]=f2bf(b.y); r[6]=f2bf(b.z); r[7]=f2bf(b.w);
  *(u16x8*)(dst + off) = r;
}

// Barrier-free streaming GEMM: out[M][512] = (A_f32 @ Wb_bf16^T + bias)*scale.
// No LDS. Each wave owns a 32x64 tile; A (HBM) and B (L2-resident, 0.5 MB)
// stream straight to registers, 2-deep static prefetch (a0/b0, a1/b1).
// Block = 4 waves (2x2) sharing A/B slices via L1. VGPR budget <=128.
template<int OUT_BF16>
__global__ __launch_bounds__(256, 4) void gemm_stream(
    const float* __restrict__ A, const unsigned short* __restrict__ Wb,
    const float* __restrict__ bias, float scale, void* __restrict__ out_, int M)
{
  const int nwg = gridDim.x;                 // multiple of 8
  const int bid = blockIdx.x;
  const int wgid = (bid & 7) * (nwg >> 3) + (bid >> 3);  // bijective XCD swizzle
  const int bn = wgid & 3, bm = wgid >> 2;               // bn-inner: A-panel L2 reuse

  const int t = threadIdx.x;
  const int wid = t >> 6, lane = t & 63;
  const int wm = wid >> 1, wn = wid & 1;     // wave tile: 32 rows x 64 cols
  const int rl = lane & 15, kg = lane >> 4;

  const float* A0g = A + (size_t)(bm*64 + wm*32 + rl)*512 + kg*8;
  const float* A1g = A0g + 16*512;
  const unsigned short* B0g = Wb + (size_t)(bn*128 + wn*64 + rl)*512 + kg*8;

  f32x4 acc[2][4];
  #pragma unroll
  for (int i=0;i<2;i++)
    #pragma unroll
    for (int n=0;n<4;n++) acc[i][n] = (f32x4){0.f,0.f,0.f,0.f};

  f32x4 a0[4], a1[4];       // A stages (f32): [frag0 lo, frag0 hi, frag1 lo, frag1 hi]
  s16x8 b0[4], b1[4];       // B stages (bf16): 4 col-frags

  #define ISSA(ar, kt) do{                                  \
    ar[0] = *(const f32x4*)(A0g + (kt)*32);                 \
    ar[1] = *(const f32x4*)(A0g + (kt)*32 + 4);             \
    ar[2] = *(const f32x4*)(A1g + (kt)*32);                 \
    ar[3] = *(const f32x4*)(A1g + (kt)*32 + 4);             \
  }while(0)
  #define ISSB(br, kt) do{                                  \
    br[0] = *(const s16x8*)(B0g + (kt)*32);                 \
    br[1] = *(const s16x8*)(B0g + 16*512 + (kt)*32);        \
    br[2] = *(const s16x8*)(B0g + 32*512 + (kt)*32);        \
    br[3] = *(const s16x8*)(B0g + 48*512 + (kt)*32);        \
  }while(0)

  // 2-deep prologue
  ISSA(a0, 0); ISSB(b0, 0);
  ISSA(a1, 1); ISSB(b1, 1);

  #define STEP(ar, br, knext, cond) do{                                          \
    s16x8 af0_ = cvt8(ar[0], ar[1]);                                             \
    s16x8 af1_ = cvt8(ar[2], ar[3]);                                             \
    __builtin_amdgcn_s_setprio(1);                                               \
    _Pragma("unroll")                                                            \
    for (int n=0;n<4;n++){                                                       \
      acc[0][n] = __builtin_amdgcn_mfma_f32_16x16x32_bf16(af0_, br[n], acc[0][n],0,0,0); \
      acc[1][n] = __builtin_amdgcn_mfma_f32_16x16x32_bf16(af1_, br[n], acc[1][n],0,0,0); \
    }                                                                            \
    __builtin_amdgcn_s_setprio(0);                                               \
    if (cond){ ISSA(ar, knext); ISSB(br, knext); }                               \
  }while(0)

  for (int k2 = 0; k2 < 8; ++k2){           // two K-steps (BK=32 each) per iter
    STEP(a0, b0, 2*k2+2, k2 < 7);
    STEP(a1, b1, 2*k2+3, k2 < 7);
  }
  #undef ISSA
  #undef ISSB
  #undef STEP

  #pragma unroll
  for (int n=0;n<4;n++){
    const int gcol = bn*128 + wn*64 + n*16 + rl;
    const float bv = bias[gcol];
    #pragma unroll
    for (int i=0;i<2;i++){
      const int growb = bm*64 + wm*32 + i*16 + kg*4;
      #pragma unroll
      for (int r=0;r<4;r++){
        float v = (acc[i][n][r] + bv) * scale;
        size_t idx = (size_t)(growb + r) * 512 + gcol;
        if (OUT_BF16) ((unsigned short*)out_)[idx] = f2bf(v);
        else          ((float*)out_)[idx] = v;
      }
    }
  }
}

// partial scores over one ww-chunk: part[wwc][b*512+dd][m] = sum_{ww in chunk} Qp[b,ww,dd]*Kp[b,ww,m,dd]
__global__ __launch_bounds__(256) void scores_kernel(
    const float* __restrict__ Qp, const unsigned short* __restrict__ Kp,
    float* __restrict__ part)
{
  const int wwc = blockIdx.x, ddt = blockIdx.y, b = blockIdx.z;
  const int ww0 = wwc*64, dd0 = ddt*64;
  __shared__ float qs[64][64];
  const int t = threadIdx.x;
  {
    const int dd = t & 63, wbase = t >> 6;
    #pragma unroll
    for (int i=0;i<16;i++){
      int ww = wbase + i*4;
      qs[ww][dd] = Qp[(size_t)(b*512 + ww0 + ww)*512 + dd0 + dd];
    }
  }
  __syncthreads();
  const int g = t & 7, mr = t >> 3;
  float acc[2][8];
  #pragma unroll
  for (int r=0;r<2;r++)
    #pragma unroll
    for (int j=0;j<8;j++) acc[r][j] = 0.f;

  for (int ww=0; ww<64; ww++){
    float4 q0 = *(const float4*)&qs[ww][g*8];
    float4 q1 = *(const float4*)&qs[ww][g*8+4];
    float qv[8] = {q0.x,q0.y,q0.z,q0.w,q1.x,q1.y,q1.z,q1.w};
    #pragma unroll
    for (int r=0;r<2;r++){
      const int m = mr + r*32;
      u16x8 kv = *(const u16x8*)&Kp[((size_t)(b*512 + ww0 + ww)*64 + m)*512 + dd0 + g*8];
      #pragma unroll
      for (int j=0;j<8;j++) acc[r][j] += qv[j] * bf2f(kv[j]);
    }
  }
  #pragma unroll
  for (int r=0;r<2;r++){
    const int m = mr + r*32;
    #pragma unroll
    for (int j=0;j<8;j++){
      const int dd = dd0 + g*8 + j;
      part[(size_t)wwc*131072 + (size_t)(b*512 + dd)*64 + m] = acc[r][j];
    }
  }
}

__global__ __launch_bounds__(256) void softmax_kernel(
    const float* __restrict__ part, float* __restrict__ attn)
{
  const int row = blockIdx.x*4 + (threadIdx.x >> 6);
  const int m = threadIdx.x & 63;
  float v = 0.f;
  #pragma unroll
  for (int c=0;c<8;c++) v += part[(size_t)c*131072 + (size_t)row*64 + m];
  float mx = v;
  #pragma unroll
  for (int o=32;o>=1;o>>=1) mx = fmaxf(mx, __shfl_xor(mx, o));
  float e = __expf(v - mx);
  float s = e;
  #pragma unroll
  for (int o=32;o>=1;o>>=1) s += __shfl_xor(s, o);
  attn[(size_t)row*64 + m] = e / s;
}

__global__ __launch_bounds__(256) void pv_kernel(
    const float* __restrict__ attn, const unsigned short* __restrict__ Vp,
    float* __restrict__ att_out)
{
  const int wwc = blockIdx.x, ddt = blockIdx.y, b = blockIdx.z;
  const int ww0 = wwc*64, dd0 = ddt*64;
  __shared__ float as_[64][72];
  const int t = threadIdx.x;
  {
    const int m = t & 63, dbase = t >> 6;
    #pragma unroll
    for (int i=0;i<16;i++){
      int dd = dbase + i*4;
      as_[m][dd] = attn[(size_t)(b*512 + dd0 + dd)*64 + m];
    }
  }
  __syncthreads();
  const int g = t & 7, wr = t >> 3;
  float acc[2][8];
  #pragma unroll
  for (int r=0;r<2;r++)
    #pragma unroll
    for (int j=0;j<8;j++) acc[r][j] = 0.f;

  for (int m=0;m<64;m++){
    float4 a0 = *(const float4*)&as_[m][g*8];
    float4 a1 = *(const float4*)&as_[m][g*8+4];
    float av[8] = {a0.x,a0.y,a0.z,a0.w,a1.x,a1.y,a1.z,a1.w};
    #pragma unroll
    for (int r=0;r<2;r++){
      const int ww = wr + r*32;
      u16x8 vv = *(const u16x8*)&Vp[((size_t)(b*512 + ww0 + ww)*64 + m)*512 + dd0 + g*8];
      #pragma unroll
      for (int j=0;j<8;j++) acc[r][j] += av[j] * bf2f(vv[j]);
    }
  }
  #pragma unroll
  for (int r=0;r<2;r++){
    const int ww = ww0 + wr + r*32;
    float4 o0 = {acc[r][0],acc[r][1],acc[r][2],acc[r][3]};
    float4 o1 = {acc[r][4],acc[r][5],acc[r][6],acc[r][7]};
    float* dst = &att_out[(size_t)(ww*4 + b)*512 + dd0 + g*8];
    *(float4*)dst = o0;
    *(float4*)(dst+4) = o1;
  }
}

extern "C" void kernel_launch(void* const* d_in, const int* in_sizes, int n_in,
                              void* d_out, int out_size, void* d_ws, size_t ws_size,
                              hipStream_t stream) {
  const float* Q  = (const float*)d_in[0];
  const float* K  = (const float*)d_in[1];
  const float* V  = (const float*)d_in[2];
  const float* Wq = (const float*)d_in[3];
  const float* bq = (const float*)d_in[4];
  const float* Wk = (const float*)d_in[5];
  const float* bk = (const float*)d_in[6];
  const float* Wv = (const float*)d_in[7];
  const float* bv = (const float*)d_in[8];
  const float* Wp = (const float*)d_in[9];
  const float* bp = (const float*)d_in[10];
  float* out = (float*)d_out;

  char* ws = (char*)d_ws;
  float* Qp       = (float*)(ws);                       // 4 MiB
  float* part     = (float*)(ws + ((size_t)4<<20));     // 4 MiB (reused as att_out)
  float* att_out  = part;
  float* attn     = (float*)(ws + ((size_t)8<<20));     // 0.5 MiB
  unsigned short* Wqb = (unsigned short*)(ws + ((size_t)9<<20));
  unsigned short* Wkb = Wqb + 262144;
  unsigned short* Wvb = Wkb + 262144;
  unsigned short* Wpb = Wvb + 262144;                   // 2 MiB total
  unsigned short* KVp = (unsigned short*)(ws + ((size_t)11<<20)); // 128 MiB

  const float qscale = 0.044194173824159223f;  // 1/sqrt(512)

  cast_w<<<512, 256, 0, stream>>>(Wq, Wk, Wv, Wp, Wqb, Wkb, Wvb, Wpb);

  // Q projection (+bias, /sqrt(d)) -> f32
  gemm_stream<0><<<128, 256, 0, stream>>>(Q, Wqb, bq, qscale, Qp, 2048);
  // K projection -> bf16
  gemm_stream<1><<<8192, 256, 0, stream>>>(K, Wkb, bk, 1.f, KVp, 131072);
  scores_kernel<<<dim3(8,8,4), 256, 0, stream>>>(Qp, KVp, part);
  softmax_kernel<<<512, 256, 0, stream>>>(part, attn);
  // V projection reuses KVp (stream-ordered after scores)
  gemm_stream<1><<<8192, 256, 0, stream>>>(V, Wvb, bv, 1.f, KVp, 131072);
  pv_kernel<<<dim3(8,8,4), 256, 0, stream>>>(attn, KVp, att_out);
  // output projection -> d_out
  gemm_stream<0><<<128, 256, 0, stream>>>(att_out, Wpb, bp, 1.f, out, 2048);
}

// Round 7
// 457.764 us; speedup vs baseline: 2.2891x; 2.2891x over previous
//
#include <hip/hip_runtime.h>
#include <hip/hip_bf16.h>

typedef short s16x8 __attribute__((ext_vector_type(8)));
typedef float f32x4 __attribute__((ext_vector_type(4)));
typedef unsigned short u16x8 __attribute__((ext_vector_type(8)));

__device__ __forceinline__ float bf2f(unsigned short u){
  union { unsigned int i; float f; } v; v.i = ((unsigned int)u) << 16; return v.f;
}
__device__ __forceinline__ unsigned short f2bf(float f){
  union { float f; unsigned int i; } v; v.f = f;
  unsigned int x = v.i;
  return (unsigned short)((x + 0x7fffu + ((x >> 16) & 1u)) >> 16);
}
__device__ __forceinline__ short f2bs(float f){
  union { __hip_bfloat16 h; short s; } u; u.h = __float2bfloat16(f); return u.s;
}
__device__ __forceinline__ s16x8 cvt8(f32x4 a, f32x4 b){
  s16x8 r;
  r[0]=f2bs(a[0]); r[1]=f2bs(a[1]); r[2]=f2bs(a[2]); r[3]=f2bs(a[3]);
  r[4]=f2bs(b[0]); r[5]=f2bs(b[1]); r[6]=f2bs(b[2]); r[7]=f2bs(b[3]);
  return r;
}

__device__ __forceinline__ void gload16(const void* g, void* l){
  __builtin_amdgcn_global_load_lds(
      (__attribute__((address_space(1))) void*)(g),
      (__attribute__((address_space(3))) void*)(l), 16, 0, 0);
}

// cast the 4 weight matrices (512x512 f32) to bf16 in one launch
__global__ __launch_bounds__(256) void cast_w(
    const float* __restrict__ w0, const float* __restrict__ w1,
    const float* __restrict__ w2, const float* __restrict__ w3,
    unsigned short* __restrict__ o0, unsigned short* __restrict__ o1,
    unsigned short* __restrict__ o2, unsigned short* __restrict__ o3)
{
  int g = blockIdx.x * 256 + threadIdx.x;
  int which = g >> 15;
  int off = (g & 32767) * 8;
  const float* src = which==0 ? w0 : which==1 ? w1 : which==2 ? w2 : w3;
  unsigned short* dst = which==0 ? o0 : which==1 ? o1 : which==2 ? o2 : o3;
  float4 a = *(const float4*)(src + off);
  float4 b = *(const float4*)(src + off + 4);
  u16x8 r;
  r[0]=f2bf(a.x); r[1]=f2bf(a.y); r[2]=f2bf(a.z); r[3]=f2bf(a.w);
  r[4]=f2bf(b.x); r[5]=f2bf(b.y); r[6]=f2bf(b.z); r[7]=f2bf(b.w);
  *(u16x8*)(dst + off) = r;
}

// m201-style multi-phase GEMM: out[M][512] = (A_f32 @ Wb_bf16^T + bias)*scale
// Tile 128M x 256N, 8 waves (2x4), K=512 as 16 half-phases of 32.
// Per phase: vmcnt(8) -> barrier -> ds_read(swz) -> STAGE(ph+3) -> MFMA -> barrier.
// 3 half-tiles always in flight via counted vmcnt (never 0 until drain).
template<int OUT_BF16>
__global__ __launch_bounds__(512, 2) void gemm_mp(
    const float* __restrict__ A, const unsigned short* __restrict__ Wb,
    const float* __restrict__ bias, float scale, void* __restrict__ out_, int M)
{
  __shared__ float          As[2][2][128*32];  // [tilebuf][half] 16KB each = 64KB
  __shared__ unsigned short Bs[2][2][256*32];  // 16KB each = 64KB   (total 128KB)

  const int nwg = gridDim.x;                   // multiple of 8
  const int bid = blockIdx.x;
  const int wgid = (bid & 7) * (nwg >> 3) + (bid >> 3);  // bijective XCD swizzle
  const int bn = wgid & 1, bm = wgid >> 1;               // bn-inner: A-panel reuse

  const int t = threadIdx.x;
  const int wid = t >> 6, lane = t & 63;
  const int wm = wid >> 2, wn = wid & 3;       // 2 x 4 waves, wave tile 64x64
  const int rl = lane & 15, kg = lane >> 4;

  const float* Ab = A + (size_t)bm*128*512;
  const unsigned short* Wgb = Wb + (size_t)bn*256*512;

  // DMA lane decomposition
  const int l3 = lane >> 3, l7 = lane & 7;     // A: row-sub / phys slot (16B)
  const int l2 = lane >> 2, lb3 = lane & 3;    // B: col-sub / phys slot (16B)

  // stage half-phase ph (k0 = ph*32): A 128x32 f32, B 256x32 bf16,
  // linear LDS dest, pre-swizzled per-lane global source (inverse XOR).
  #define STAGE(ph) do {                                                        \
    const int k0_ = (ph)*32;                                                    \
    float* adst = &As[((ph)>>1)&1][(ph)&1][0];                                  \
    unsigned short* bdst = &Bs[((ph)>>1)&1][(ph)&1][0];                         \
    _Pragma("unroll")                                                           \
    for (int j=0;j<2;++j){                                                      \
      int arow = j*64 + wid*8 + l3;                                             \
      gload16(Ab + (size_t)arow*512 + k0_ + ((l7 ^ l3) << 2),                   \
              adst + (j*64 + wid*8)*32);                                        \
      int bcol = j*128 + wid*16 + l2;                                           \
      gload16(Wgb + (size_t)bcol*512 + k0_ + (((lb3 ^ (l2&3))) << 3),           \
              bdst + (j*128 + wid*16)*32);                                      \
    }                                                                           \
  } while(0)

  f32x4 acc[4][4];
  #pragma unroll
  for (int m=0;m<4;m++)
    #pragma unroll
    for (int n=0;n<4;n++) acc[m][n] = (f32x4){0.f,0.f,0.f,0.f};

  // prologue: 3 half-tiles in flight (12 loads/thread)
  STAGE(0); STAGE(1); STAGE(2);

  #pragma unroll 4
  for (int ph = 0; ph < 16; ++ph){
    // counted wait: H(ph) landed; H(ph+1), H(ph+2) stay in flight
    if (ph <= 13)      asm volatile("s_waitcnt vmcnt(8)" ::: "memory");
    else if (ph == 14) asm volatile("s_waitcnt vmcnt(4)" ::: "memory");
    else               asm volatile("s_waitcnt vmcnt(0)" ::: "memory");
    asm volatile("s_barrier" ::: "memory");

    const int pb = (ph>>1)&1, hb = ph&1;
    const float* ah = &As[pb][hb][0];
    const unsigned short* bh = &Bs[pb][hb][0];

    s16x8 af[4], bw[4];
    #pragma unroll
    for (int m=0;m<4;m++){
      const int row = wm*64 + m*16 + rl;
      f32x4 x0 = *(const f32x4*)(ah + row*32 + (((2*kg  ) ^ (row&7)) << 2));
      f32x4 x1 = *(const f32x4*)(ah + row*32 + (((2*kg+1) ^ (row&7)) << 2));
      af[m] = cvt8(x0, x1);
    }
    #pragma unroll
    for (int n=0;n<4;n++){
      const int col = wn*64 + n*16 + rl;
      bw[n] = *(const s16x8*)(bh + col*32 + ((kg ^ (col&3)) << 3));
    }

    if (ph + 3 < 16) STAGE(ph + 3);   // issue next; lands >= 3 phases later

    __builtin_amdgcn_s_setprio(1);
    #pragma unroll
    for (int m=0;m<4;m++)
      #pragma unroll
      for (int n=0;n<4;n++)
        acc[m][n] = __builtin_amdgcn_mfma_f32_16x16x32_bf16(af[m], bw[n], acc[m][n], 0, 0, 0);
    __builtin_amdgcn_s_setprio(0);

    asm volatile("s_barrier" ::: "memory");   // readers retired before overwrite
  }
  #undef STAGE

  #pragma unroll
  for (int n=0;n<4;n++){
    const int gcol = bn*256 + wn*64 + n*16 + rl;
    const float bv = bias[gcol];
    #pragma unroll
    for (int m=0;m<4;m++){
      const int growb = bm*128 + wm*64 + m*16 + kg*4;
      #pragma unroll
      for (int r=0;r<4;r++){
        float v = (acc[m][n][r] + bv) * scale;
        size_t idx = (size_t)(growb + r) * 512 + gcol;
        if (OUT_BF16) ((unsigned short*)out_)[idx] = f2bf(v);
        else          ((float*)out_)[idx] = v;
      }
    }
  }
}

// partial scores over one ww-chunk: part[wwc][b*512+dd][m] = sum_{ww in chunk} Qp[b,ww,dd]*Kp[b,ww,m,dd]
__global__ __launch_bounds__(256) void scores_kernel(
    const float* __restrict__ Qp, const unsigned short* __restrict__ Kp,
    float* __restrict__ part)
{
  const int wwc = blockIdx.x, ddt = blockIdx.y, b = blockIdx.z;
  const int ww0 = wwc*64, dd0 = ddt*64;
  __shared__ float qs[64][64];
  const int t = threadIdx.x;
  {
    const int dd = t & 63, wbase = t >> 6;
    #pragma unroll
    for (int i=0;i<16;i++){
      int ww = wbase + i*4;
      qs[ww][dd] = Qp[(size_t)(b*512 + ww0 + ww)*512 + dd0 + dd];
    }
  }
  __syncthreads();
  const int g = t & 7, mr = t >> 3;
  float acc[2][8];
  #pragma unroll
  for (int r=0;r<2;r++)
    #pragma unroll
    for (int j=0;j<8;j++) acc[r][j] = 0.f;

  for (int ww=0; ww<64; ww++){
    float4 q0 = *(const float4*)&qs[ww][g*8];
    float4 q1 = *(const float4*)&qs[ww][g*8+4];
    float qv[8] = {q0.x,q0.y,q0.z,q0.w,q1.x,q1.y,q1.z,q1.w};
    #pragma unroll
    for (int r=0;r<2;r++){
      const int m = mr + r*32;
      u16x8 kv = *(const u16x8*)&Kp[((size_t)(b*512 + ww0 + ww)*64 + m)*512 + dd0 + g*8];
      #pragma unroll
      for (int j=0;j<8;j++) acc[r][j] += qv[j] * bf2f(kv[j]);
    }
  }
  #pragma unroll
  for (int r=0;r<2;r++){
    const int m = mr + r*32;
    #pragma unroll
    for (int j=0;j<8;j++){
      const int dd = dd0 + g*8 + j;
      part[(size_t)wwc*131072 + (size_t)(b*512 + dd)*64 + m] = acc[r][j];
    }
  }
}

__global__ __launch_bounds__(256) void softmax_kernel(
    const float* __restrict__ part, float* __restrict__ attn)
{
  const int row = blockIdx.x*4 + (threadIdx.x >> 6);
  const int m = threadIdx.x & 63;
  float v = 0.f;
  #pragma unroll
  for (int c=0;c<8;c++) v += part[(size_t)c*131072 + (size_t)row*64 + m];
  float mx = v;
  #pragma unroll
  for (int o=32;o>=1;o>>=1) mx = fmaxf(mx, __shfl_xor(mx, o));
  float e = __expf(v - mx);
  float s = e;
  #pragma unroll
  for (int o=32;o>=1;o>>=1) s += __shfl_xor(s, o);
  attn[(size_t)row*64 + m] = e / s;
}

__global__ __launch_bounds__(256) void pv_kernel(
    const float* __restrict__ attn, const unsigned short* __restrict__ Vp,
    float* __restrict__ att_out)
{
  const int wwc = blockIdx.x, ddt = blockIdx.y, b = blockIdx.z;
  const int ww0 = wwc*64, dd0 = ddt*64;
  __shared__ float as_[64][72];
  const int t = threadIdx.x;
  {
    const int m = t & 63, dbase = t >> 6;
    #pragma unroll
    for (int i=0;i<16;i++){
      int dd = dbase + i*4;
      as_[m][dd] = attn[(size_t)(b*512 + dd0 + dd)*64 + m];
    }
  }
  __syncthreads();
  const int g = t & 7, wr = t >> 3;
  float acc[2][8];
  #pragma unroll
  for (int r=0;r<2;r++)
    #pragma unroll
    for (int j=0;j<8;j++) acc[r][j] = 0.f;

  for (int m=0;m<64;m++){
    float4 a0 = *(const float4*)&as_[m][g*8];
    float4 a1 = *(const float4*)&as_[m][g*8+4];
    float av[8] = {a0.x,a0.y,a0.z,a0.w,a1.x,a1.y,a1.z,a1.w};
    #pragma unroll
    for (int r=0;r<2;r++){
      const int ww = wr + r*32;
      u16x8 vv = *(const u16x8*)&Vp[((size_t)(b*512 + ww0 + ww)*64 + m)*512 + dd0 + g*8];
      #pragma unroll
      for (int j=0;j<8;j++) acc[r][j] += av[j] * bf2f(vv[j]);
    }
  }
  #pragma unroll
  for (int r=0;r<2;r++){
    const int ww = ww0 + wr + r*32;
    float4 o0 = {acc[r][0],acc[r][1],acc[r][2],acc[r][3]};
    float4 o1 = {acc[r][4],acc[r][5],acc[r][6],acc[r][7]};
    float* dst = &att_out[(size_t)(ww*4 + b)*512 + dd0 + g*8];
    *(float4*)dst = o0;
    *(float4*)(dst+4) = o1;
  }
}

extern "C" void kernel_launch(void* const* d_in, const int* in_sizes, int n_in,
                              void* d_out, int out_size, void* d_ws, size_t ws_size,
                              hipStream_t stream) {
  const float* Q  = (const float*)d_in[0];
  const float* K  = (const float*)d_in[1];
  const float* V  = (const float*)d_in[2];
  const float* Wq = (const float*)d_in[3];
  const float* bq = (const float*)d_in[4];
  const float* Wk = (const float*)d_in[5];
  const float* bk = (const float*)d_in[6];
  const float* Wv = (const float*)d_in[7];
  const float* bv = (const float*)d_in[8];
  const float* Wp = (const float*)d_in[9];
  const float* bp = (const float*)d_in[10];
  float* out = (float*)d_out;

  char* ws = (char*)d_ws;
  float* Qp       = (float*)(ws);                       // 4 MiB
  float* part     = (float*)(ws + ((size_t)4<<20));     // 4 MiB (reused as att_out)
  float* att_out  = part;
  float* attn     = (float*)(ws + ((size_t)8<<20));     // 0.5 MiB
  unsigned short* Wqb = (unsigned short*)(ws + ((size_t)9<<20));
  unsigned short* Wkb = Wqb + 262144;
  unsigned short* Wvb = Wkb + 262144;
  unsigned short* Wpb = Wvb + 262144;                   // 2 MiB total
  unsigned short* KVp = (unsigned short*)(ws + ((size_t)11<<20)); // 128 MiB

  const float qscale = 0.044194173824159223f;  // 1/sqrt(512)

  cast_w<<<512, 256, 0, stream>>>(Wq, Wk, Wv, Wp, Wqb, Wkb, Wvb, Wpb);

  // Q projection (+bias, /sqrt(d)) -> f32
  gemm_mp<0><<<32, 512, 0, stream>>>(Q, Wqb, bq, qscale, Qp, 2048);
  // K projection -> bf16
  gemm_mp<1><<<2048, 512, 0, stream>>>(K, Wkb, bk, 1.f, KVp, 131072);
  scores_kernel<<<dim3(8,8,4), 256, 0, stream>>>(Qp, KVp, part);
  softmax_kernel<<<512, 256, 0, stream>>>(part, attn);
  // V projection reuses KVp (stream-ordered after scores)
  gemm_mp<1><<<2048, 512, 0, stream>>>(V, Wvb, bv, 1.f, KVp, 131072);
  pv_kernel<<<dim3(8,8,4), 256, 0, stream>>>(attn, KVp, att_out);
  // output projection -> d_out
  gemm_mp<0><<<32, 512, 0, stream>>>(att_out, Wpb, bp, 1.f, out, 2048);
}

// Round 8
// 384.861 us; speedup vs baseline: 2.7227x; 1.1894x over previous
//
#include <hip/hip_runtime.h>
#include <hip/hip_bf16.h>

typedef short s16x8 __attribute__((ext_vector_type(8)));
typedef float f32x4 __attribute__((ext_vector_type(4)));
typedef unsigned short u16x8 __attribute__((ext_vector_type(8)));

__device__ __forceinline__ float bf2f(unsigned short u){
  union { unsigned int i; float f; } v; v.i = ((unsigned int)u) << 16; return v.f;
}
__device__ __forceinline__ unsigned short f2bf(float f){
  union { float f; unsigned int i; } v; v.f = f;
  unsigned int x = v.i;
  return (unsigned short)((x + 0x7fffu + ((x >> 16) & 1u)) >> 16);
}
__device__ __forceinline__ short f2bs(float f){
  union { __hip_bfloat16 h; short s; } u; u.h = __float2bfloat16(f); return u.s;
}
__device__ __forceinline__ s16x8 cvt8(f32x4 a, f32x4 b){
  s16x8 r;
  r[0]=f2bs(a[0]); r[1]=f2bs(a[1]); r[2]=f2bs(a[2]); r[3]=f2bs(a[3]);
  r[4]=f2bs(b[0]); r[5]=f2bs(b[1]); r[6]=f2bs(b[2]); r[7]=f2bs(b[3]);
  return r;
}

__device__ __forceinline__ void gload16(const void* g, void* l){
  __builtin_amdgcn_global_load_lds(
      (__attribute__((address_space(1))) void*)(g),
      (__attribute__((address_space(3))) void*)(l), 16, 0, 0);
}

// cast the 4 weight matrices (512x512 f32) to bf16 in one launch
__global__ __launch_bounds__(256) void cast_w(
    const float* __restrict__ w0, const float* __restrict__ w1,
    const float* __restrict__ w2, const float* __restrict__ w3,
    unsigned short* __restrict__ o0, unsigned short* __restrict__ o1,
    unsigned short* __restrict__ o2, unsigned short* __restrict__ o3)
{
  int g = blockIdx.x * 256 + threadIdx.x;
  int which = g >> 15;
  int off = (g & 32767) * 8;
  const float* src = which==0 ? w0 : which==1 ? w1 : which==2 ? w2 : w3;
  unsigned short* dst = which==0 ? o0 : which==1 ? o1 : which==2 ? o2 : o3;
  float4 a = *(const float4*)(src + off);
  float4 b = *(const float4*)(src + off + 4);
  u16x8 r;
  r[0]=f2bf(a.x); r[1]=f2bf(a.y); r[2]=f2bf(a.z); r[3]=f2bf(a.w);
  r[4]=f2bf(b.x); r[5]=f2bf(b.y); r[6]=f2bf(b.z); r[7]=f2bf(b.w);
  *(u16x8*)(dst + off) = r;
}

// Multi-tile rolling-pipeline GEMM: out[M][512] = (A_f32 @ Wb^T + bias)*scale.
// Block: 512 thr (8 waves, 4x2), tile 128x256, NT M-tiles per block through
// one continuously-primed 4-slot LDS pipeline. Counted vmcnt (63 at tile
// boundaries to ride over epilogue stores in the FIFO, 8 steady, 4/0 drain).
template<int OUT_BF16, int NT>
__global__ __launch_bounds__(512, 1) void gemm_mt(
    const float* __restrict__ A, const unsigned short* __restrict__ Wb,
    const float* __restrict__ bias, float scale, void* __restrict__ out_)
{
  __shared__ float          As[4][128*32];   // 4 x 16KB
  __shared__ unsigned short Bs[4][256*32];   // 4 x 16KB  (total 128KB)

  const int nwg = gridDim.x;                 // multiple of 8
  const int bid = blockIdx.x;
  const int wgid = (bid & 7) * (nwg >> 3) + (bid >> 3);  // bijective XCD swizzle
  const int bn = wgid & 1;                   // bn-inner: A-panel L2 reuse
  const int bmg = wgid >> 1;                 // covers NT tiles of 128 rows

  const int t = threadIdx.x;
  const int wid = t >> 6, lane = t & 63;
  const int wm = wid >> 1, wn = wid & 1;     // 4x2 waves; wave tile 32 x 128
  const int rl = lane & 15, kg = lane >> 4;

  const float* Ab0 = A + (size_t)bmg * (NT * 128) * 512;
  const unsigned short* Wgb = Wb + (size_t)bn * 256 * 512;

  const int l3 = lane >> 3, l7 = lane & 7;   // A: row-sub / phys 16B slot
  const int l2 = lane >> 2, lb3 = lane & 3;  // B: col-sub / phys 16B slot

  // stage global phase gph (tile gph>>4, k-phase gph&15) into slot gph&3.
  // Linear LDS dest; per-lane pre-swizzled global source (read undoes XOR).
  #define STAGE(gph) do {                                                    \
    const int tau_ = (gph) >> 4, p_ = (gph) & 15, sl_ = (gph) & 3;           \
    const int k0_ = p_ * 32;                                                 \
    const float* Abase_ = Ab0 + (size_t)tau_ * 128 * 512;                    \
    _Pragma("unroll")                                                        \
    for (int j = 0; j < 2; ++j){                                             \
      int arow = j*64 + wid*8 + l3;                                          \
      gload16(Abase_ + (size_t)arow*512 + k0_ + ((l7 ^ l3) << 2),            \
              &As[sl_][(j*64 + wid*8)*32]);                                  \
      int bcol = j*128 + wid*16 + l2;                                        \
      gload16(Wgb + (size_t)bcol*512 + k0_ + ((lb3 ^ (l2&3)) << 3),          \
              &Bs[sl_][(j*128 + wid*16)*32]);                                \
    }                                                                        \
  } while(0)

  f32x4 acc[2][8];
  #pragma unroll
  for (int m=0;m<2;m++)
    #pragma unroll
    for (int n=0;n<8;n++) acc[m][n] = (f32x4){0.f,0.f,0.f,0.f};

  // prologue: 3 phases in flight (12 loads/thread)
  STAGE(0); STAGE(1); STAGE(2);

  for (int tau = 0; tau < NT; ++tau){
    #pragma unroll
    for (int p = 0; p < 16; ++p){
      // FIFO-counted wait (4 loads/stage; 64 stores ride in queue at boundary)
      if (NT > 1 && tau > 0 && p < 3)
        asm volatile("s_waitcnt vmcnt(63)" ::: "memory");
      else if (tau == NT-1 && p == 14)
        asm volatile("s_waitcnt vmcnt(4)" ::: "memory");
      else if (tau == NT-1 && p == 15)
        asm volatile("s_waitcnt vmcnt(0)" ::: "memory");
      else
        asm volatile("s_waitcnt vmcnt(8)" ::: "memory");
      asm volatile("s_barrier" ::: "memory");

      const int sl = p & 3;
      const float* ah = &As[sl][0];
      const unsigned short* bh = &Bs[sl][0];

      s16x8 af[2], bw[8];
      #pragma unroll
      for (int m=0;m<2;m++){
        const int row = wm*32 + m*16 + rl;
        f32x4 x0 = *(const f32x4*)(ah + row*32 + (((2*kg  ) ^ (row&7)) << 2));
        f32x4 x1 = *(const f32x4*)(ah + row*32 + (((2*kg+1) ^ (row&7)) << 2));
        af[m] = cvt8(x0, x1);
      }
      #pragma unroll
      for (int n=0;n<8;n++){
        const int col = wn*128 + n*16 + rl;
        bw[n] = *(const s16x8*)(bh + col*32 + ((kg ^ (col&3)) << 3));
      }

      {
        const int gph = tau*16 + p + 3;
        if (gph < NT*16) STAGE(gph);   // lands >= 3 phases later
      }

      __builtin_amdgcn_s_setprio(1);
      #pragma unroll
      for (int m=0;m<2;m++)
        #pragma unroll
        for (int n=0;n<8;n++)
          acc[m][n] = __builtin_amdgcn_mfma_f32_16x16x32_bf16(af[m], bw[n], acc[m][n], 0, 0, 0);
      __builtin_amdgcn_s_setprio(0);

      if (p == 15){
        // epilogue for tile tau (stores enter VM queue newest; accounted above)
        #pragma unroll
        for (int n=0;n<8;n++){
          const int gcol = bn*256 + wn*128 + n*16 + rl;
          const float bv = bias[gcol];
          #pragma unroll
          for (int m=0;m<2;m++){
            const int growb = (bmg*NT + tau)*128 + wm*32 + m*16 + kg*4;
            #pragma unroll
            for (int r=0;r<4;r++){
              float v = (acc[m][n][r] + bv) * scale;
              size_t idx = (size_t)(growb + r) * 512 + gcol;
              if (OUT_BF16) ((unsigned short*)out_)[idx] = f2bf(v);
              else          ((float*)out_)[idx] = v;
            }
            acc[m][n] = (f32x4){0.f,0.f,0.f,0.f};
          }
        }
      }

      asm volatile("s_barrier" ::: "memory");   // readers retired before slot reuse
    }
  }
  #undef STAGE
}

// partial scores over one ww-chunk: part[wwc][b*512+dd][m] = sum_{ww in chunk} Qp[b,ww,dd]*Kp[b,ww,m,dd]
__global__ __launch_bounds__(256) void scores_kernel(
    const float* __restrict__ Qp, const unsigned short* __restrict__ Kp,
    float* __restrict__ part)
{
  const int wwc = blockIdx.x, ddt = blockIdx.y, b = blockIdx.z;
  const int ww0 = wwc*64, dd0 = ddt*64;
  __shared__ float qs[64][64];
  const int t = threadIdx.x;
  {
    const int dd = t & 63, wbase = t >> 6;
    #pragma unroll
    for (int i=0;i<16;i++){
      int ww = wbase + i*4;
      qs[ww][dd] = Qp[(size_t)(b*512 + ww0 + ww)*512 + dd0 + dd];
    }
  }
  __syncthreads();
  const int g = t & 7, mr = t >> 3;
  float acc[2][8];
  #pragma unroll
  for (int r=0;r<2;r++)
    #pragma unroll
    for (int j=0;j<8;j++) acc[r][j] = 0.f;

  for (int ww=0; ww<64; ww++){
    float4 q0 = *(const float4*)&qs[ww][g*8];
    float4 q1 = *(const float4*)&qs[ww][g*8+4];
    float qv[8] = {q0.x,q0.y,q0.z,q0.w,q1.x,q1.y,q1.z,q1.w};
    #pragma unroll
    for (int r=0;r<2;r++){
      const int m = mr + r*32;
      u16x8 kv = *(const u16x8*)&Kp[((size_t)(b*512 + ww0 + ww)*64 + m)*512 + dd0 + g*8];
      #pragma unroll
      for (int j=0;j<8;j++) acc[r][j] += qv[j] * bf2f(kv[j]);
    }
  }
  #pragma unroll
  for (int r=0;r<2;r++){
    const int m = mr + r*32;
    #pragma unroll
    for (int j=0;j<8;j++){
      const int dd = dd0 + g*8 + j;
      part[(size_t)wwc*131072 + (size_t)(b*512 + dd)*64 + m] = acc[r][j];
    }
  }
}

__global__ __launch_bounds__(256) void softmax_kernel(
    const float* __restrict__ part, float* __restrict__ attn)
{
  const int row = blockIdx.x*4 + (threadIdx.x >> 6);
  const int m = threadIdx.x & 63;
  float v = 0.f;
  #pragma unroll
  for (int c=0;c<8;c++) v += part[(size_t)c*131072 + (size_t)row*64 + m];
  float mx = v;
  #pragma unroll
  for (int o=32;o>=1;o>>=1) mx = fmaxf(mx, __shfl_xor(mx, o));
  float e = __expf(v - mx);
  float s = e;
  #pragma unroll
  for (int o=32;o>=1;o>>=1) s += __shfl_xor(s, o);
  attn[(size_t)row*64 + m] = e / s;
}

__global__ __launch_bounds__(256) void pv_kernel(
    const float* __restrict__ attn, const unsigned short* __restrict__ Vp,
    float* __restrict__ att_out)
{
  const int wwc = blockIdx.x, ddt = blockIdx.y, b = blockIdx.z;
  const int ww0 = wwc*64, dd0 = ddt*64;
  __shared__ float as_[64][72];
  const int t = threadIdx.x;
  {
    const int m = t & 63, dbase = t >> 6;
    #pragma unroll
    for (int i=0;i<16;i++){
      int dd = dbase + i*4;
      as_[m][dd] = attn[(size_t)(b*512 + dd0 + dd)*64 + m];
    }
  }
  __syncthreads();
  const int g = t & 7, wr = t >> 3;
  float acc[2][8];
  #pragma unroll
  for (int r=0;r<2;r++)
    #pragma unroll
    for (int j=0;j<8;j++) acc[r][j] = 0.f;

  for (int m=0;m<64;m++){
    float4 a0 = *(const float4*)&as_[m][g*8];
    float4 a1 = *(const float4*)&as_[m][g*8+4];
    float av[8] = {a0.x,a0.y,a0.z,a0.w,a1.x,a1.y,a1.z,a1.w};
    #pragma unroll
    for (int r=0;r<2;r++){
      const int ww = wr + r*32;
      u16x8 vv = *(const u16x8*)&Vp[((size_t)(b*512 + ww0 + ww)*64 + m)*512 + dd0 + g*8];
      #pragma unroll
      for (int j=0;j<8;j++) acc[r][j] += av[j] * bf2f(vv[j]);
    }
  }
  #pragma unroll
  for (int r=0;r<2;r++){
    const int ww = ww0 + wr + r*32;
    float4 o0 = {acc[r][0],acc[r][1],acc[r][2],acc[r][3]};
    float4 o1 = {acc[r][4],acc[r][5],acc[r][6],acc[r][7]};
    float* dst = &att_out[(size_t)(ww*4 + b)*512 + dd0 + g*8];
    *(float4*)dst = o0;
    *(float4*)(dst+4) = o1;
  }
}

extern "C" void kernel_launch(void* const* d_in, const int* in_sizes, int n_in,
                              void* d_out, int out_size, void* d_ws, size_t ws_size,
                              hipStream_t stream) {
  const float* Q  = (const float*)d_in[0];
  const float* K  = (const float*)d_in[1];
  const float* V  = (const float*)d_in[2];
  const float* Wq = (const float*)d_in[3];
  const float* bq = (const float*)d_in[4];
  const float* Wk = (const float*)d_in[5];
  const float* bk = (const float*)d_in[6];
  const float* Wv = (const float*)d_in[7];
  const float* bv = (const float*)d_in[8];
  const float* Wp = (const float*)d_in[9];
  const float* bp = (const float*)d_in[10];
  float* out = (float*)d_out;

  char* ws = (char*)d_ws;
  float* Qp       = (float*)(ws);                       // 4 MiB
  float* part     = (float*)(ws + ((size_t)4<<20));     // 4 MiB (reused as att_out)
  float* att_out  = part;
  float* attn     = (float*)(ws + ((size_t)8<<20));     // 0.5 MiB
  unsigned short* Wqb = (unsigned short*)(ws + ((size_t)9<<20));
  unsigned short* Wkb = Wqb + 262144;
  unsigned short* Wvb = Wkb + 262144;
  unsigned short* Wpb = Wvb + 262144;                   // 2 MiB total
  unsigned short* KVp = (unsigned short*)(ws + ((size_t)11<<20)); // 128 MiB

  const float qscale = 0.044194173824159223f;  // 1/sqrt(512)

  cast_w<<<512, 256, 0, stream>>>(Wq, Wk, Wv, Wp, Wqb, Wkb, Wvb, Wpb);

  // Q projection (+bias, /sqrt(d)) -> f32   (M=2048: 16 m-tiles x 2 bn = 32 blocks)
  gemm_mt<0,1><<<32, 512, 0, stream>>>(Q, Wqb, bq, qscale, Qp);
  // K projection -> bf16  (M=131072: 1024 m-tiles / NT=4 x 2 bn = 512 blocks)
  gemm_mt<1,4><<<512, 512, 0, stream>>>(K, Wkb, bk, 1.f, KVp);
  scores_kernel<<<dim3(8,8,4), 256, 0, stream>>>(Qp, KVp, part);
  softmax_kernel<<<512, 256, 0, stream>>>(part, attn);
  // V projection reuses KVp (stream-ordered after scores)
  gemm_mt<1,4><<<512, 512, 0, stream>>>(V, Wvb, bv, 1.f, KVp);
  pv_kernel<<<dim3(8,8,4), 256, 0, stream>>>(attn, KVp, att_out);
  // output projection -> d_out
  gemm_mt<0,1><<<32, 512, 0, stream>>>(att_out, Wpb, bp, 1.f, out);
}